// Round 1
// baseline (626.316 us; speedup 1.0000x reference)
//
#include <hip/hip_runtime.h>
#include <math.h>

#define B 16
#define C 256
#define CR 128
#define L 16384
#define NROW (B * C)          // 4096 rows of length L
#define THREADS 256
#define ITERS (L / 4 / THREADS)  // 16 float4 iters per thread

// ---------------------------------------------------------------------------
// Kernel 1: per-(b,c) row mean over L. One block per row, coalesced float4.
// ---------------------------------------------------------------------------
__global__ __launch_bounds__(THREADS) void row_mean_kernel(
    const float* __restrict__ x, float* __restrict__ s) {
    const int row = blockIdx.x;
    const int t = threadIdx.x;
    const float4* xr = (const float4*)(x + (size_t)row * L);

    float acc = 0.0f;
#pragma unroll
    for (int i = 0; i < ITERS; ++i) {
        float4 v = xr[t + i * THREADS];
        acc += (v.x + v.y) + (v.z + v.w);
    }
    // wave (64-lane) reduction
#pragma unroll
    for (int off = 32; off > 0; off >>= 1) acc += __shfl_down(acc, off, 64);

    __shared__ float wsum[THREADS / 64];
    if ((t & 63) == 0) wsum[t >> 6] = acc;
    __syncthreads();
    if (t == 0) {
        float tot = 0.0f;
#pragma unroll
        for (int w = 0; w < THREADS / 64; ++w) tot += wsum[w];
        s[row] = tot * (1.0f / (float)L);
    }
}

// ---------------------------------------------------------------------------
// Kernel 2: the tiny SE MLP. Single block, 256 threads.
//   h1 = s @ w1^T        [B,CR]
//   h1 = BN_train(h1; g1,b1); h1 = gelu_erf(h1)
//   h2 = h1 @ w2^T       [B,C]
//   h2 = BN_train(h2; g2,b2); gate = sigmoid(h2)
// BN train mode: stats over batch axis (16 rows), biased variance, eps=1e-5.
// ---------------------------------------------------------------------------
__global__ __launch_bounds__(THREADS) void se_mlp_kernel(
    const float* __restrict__ s_in,
    const float* __restrict__ w1, const float* __restrict__ g1, const float* __restrict__ b1,
    const float* __restrict__ w2, const float* __restrict__ g2, const float* __restrict__ b2,
    float* __restrict__ gate) {
    __shared__ float s[B * C];    // 4096 floats
    __shared__ float h1[B * CR];  // 2048 floats
    __shared__ float h2[B * C];   // 4096 floats
    const int t = threadIdx.x;

    for (int i = t; i < B * C; i += THREADS) s[i] = s_in[i];
    __syncthreads();

    // h1[b][r] = dot(s[b,:], w1[r,:])  — 2048 outputs, 8 per thread
    for (int i = t; i < B * CR; i += THREADS) {
        const int b = i / CR, r = i % CR;
        const float* sv = &s[b * C];
        const float* wv = &w1[r * C];
        float acc = 0.0f;
#pragma unroll 4
        for (int c = 0; c < C; ++c) acc = fmaf(sv[c], wv[c], acc);
        h1[i] = acc;
    }
    __syncthreads();

    // BN1 over batch + exact-erf GELU; one channel per thread (t < 128)
    if (t < CR) {
        float mu = 0.0f;
#pragma unroll
        for (int b = 0; b < B; ++b) mu += h1[b * CR + t];
        mu *= (1.0f / (float)B);
        float var = 0.0f;
#pragma unroll
        for (int b = 0; b < B; ++b) {
            float d = h1[b * CR + t] - mu;
            var = fmaf(d, d, var);
        }
        var *= (1.0f / (float)B);
        const float inv = rsqrtf(var + 1e-5f);
        const float gg = g1[t], bb = b1[t];
#pragma unroll
        for (int b = 0; b < B; ++b) {
            float v = (h1[b * CR + t] - mu) * inv * gg + bb;
            // torch nn.GELU default: 0.5*v*(1+erf(v/sqrt(2)))
            v = 0.5f * v * (1.0f + erff(v * 0.70710678118654752440f));
            h1[b * CR + t] = v;
        }
    }
    __syncthreads();

    // h2[b][c] = dot(h1[b,:], w2[c,:]) — 4096 outputs, 16 per thread
    for (int i = t; i < B * C; i += THREADS) {
        const int b = i / C, c = i % C;
        const float* gv = &h1[b * CR];
        const float* wv = &w2[c * CR];
        float acc = 0.0f;
#pragma unroll 4
        for (int r = 0; r < CR; ++r) acc = fmaf(gv[r], wv[r], acc);
        h2[i] = acc;
    }
    __syncthreads();

    // BN2 over batch + sigmoid; one channel per thread (all 256)
    {
        float mu = 0.0f;
#pragma unroll
        for (int b = 0; b < B; ++b) mu += h2[b * C + t];
        mu *= (1.0f / (float)B);
        float var = 0.0f;
#pragma unroll
        for (int b = 0; b < B; ++b) {
            float d = h2[b * C + t] - mu;
            var = fmaf(d, d, var);
        }
        var *= (1.0f / (float)B);
        const float inv = rsqrtf(var + 1e-5f);
        const float gg = g2[t], bb = b2[t];
#pragma unroll
        for (int b = 0; b < B; ++b) {
            float v = (h2[b * C + t] - mu) * inv * gg + bb;
            gate[b * C + t] = 1.0f / (1.0f + expf(-v));
        }
    }
}

// ---------------------------------------------------------------------------
// Kernel 3: out[b,c,:] = x[b,c,:] * gate[b,c]. One block per row, float4.
// ---------------------------------------------------------------------------
__global__ __launch_bounds__(THREADS) void scale_kernel(
    const float* __restrict__ x, const float* __restrict__ gate,
    float* __restrict__ out) {
    const int row = blockIdx.x;
    const int t = threadIdx.x;
    const float g = gate[row];  // same address for all lanes -> broadcast
    const float4* xr = (const float4*)(x + (size_t)row * L);
    float4* orow = (float4*)(out + (size_t)row * L);
#pragma unroll
    for (int i = 0; i < ITERS; ++i) {
        float4 v = xr[t + i * THREADS];
        v.x *= g; v.y *= g; v.z *= g; v.w *= g;
        orow[t + i * THREADS] = v;
    }
}

extern "C" void kernel_launch(void* const* d_in, const int* in_sizes, int n_in,
                              void* d_out, int out_size, void* d_ws, size_t ws_size,
                              hipStream_t stream) {
    const float* x  = (const float*)d_in[0];
    const float* w1 = (const float*)d_in[1];
    const float* g1 = (const float*)d_in[2];
    const float* b1 = (const float*)d_in[3];
    const float* w2 = (const float*)d_in[4];
    const float* g2 = (const float*)d_in[5];
    const float* b2 = (const float*)d_in[6];
    float* out = (float*)d_out;

    float* s    = (float*)d_ws;          // NROW floats
    float* gate = s + NROW;              // NROW floats

    row_mean_kernel<<<NROW, THREADS, 0, stream>>>(x, s);
    se_mlp_kernel<<<1, THREADS, 0, stream>>>(s, w1, g1, b1, w2, g2, b2, gate);
    scale_kernel<<<NROW, THREADS, 0, stream>>>(x, gate, out);
}

// Round 2
// 505.621 us; speedup vs baseline: 1.2387x; 1.2387x over previous
//
#include <hip/hip_runtime.h>
#include <math.h>

#define B 16
#define C 256
#define CR 128
#define L 16384
#define NROW (B * C)          // 4096 rows of length L
#define THREADS 256
#define ITERS (L / 4 / THREADS)  // 16 float4 iters per thread

// ---------------------------------------------------------------------------
// Kernel 1: per-(b,c) row mean over L. One block per row, coalesced float4.
// ---------------------------------------------------------------------------
__global__ __launch_bounds__(THREADS) void row_mean_kernel(
    const float* __restrict__ x, float* __restrict__ s) {
    const int row = blockIdx.x;
    const int t = threadIdx.x;
    const float4* xr = (const float4*)(x + (size_t)row * L);

    float acc = 0.0f;
#pragma unroll
    for (int i = 0; i < ITERS; ++i) {
        float4 v = xr[t + i * THREADS];
        acc += (v.x + v.y) + (v.z + v.w);
    }
#pragma unroll
    for (int off = 32; off > 0; off >>= 1) acc += __shfl_down(acc, off, 64);

    __shared__ float wsum[THREADS / 64];
    if ((t & 63) == 0) wsum[t >> 6] = acc;
    __syncthreads();
    if (t == 0) {
        float tot = 0.0f;
#pragma unroll
        for (int w = 0; w < THREADS / 64; ++w) tot += wsum[w];
        s[row] = tot * (1.0f / (float)L);
    }
}

// ---------------------------------------------------------------------------
// Kernel 2a: h1[b][r] = gelu(BN1(dot(s[b,:], w1[r,:]))). One block per r.
// 256 threads = 16 batches x 16 lanes; each lane covers 16 of 256 elements.
// ---------------------------------------------------------------------------
__global__ __launch_bounds__(256) void mlp1_kernel(
    const float* __restrict__ s, const float* __restrict__ w1,
    const float* __restrict__ g1, const float* __restrict__ b1,
    float* __restrict__ h1) {
    const int r = blockIdx.x;      // 0..127
    const int t = threadIdx.x;     // 0..255
    const int b = t >> 4;          // 0..15
    const int j = t & 15;          // 0..15

    const float4* sv = (const float4*)(s + b * C) + j * 4;
    const float4* wv = (const float4*)(w1 + r * C) + j * 4;
    float acc = 0.0f;
#pragma unroll
    for (int k = 0; k < 4; ++k) {
        float4 a = sv[k], w = wv[k];
        acc += a.x * w.x + a.y * w.y + a.z * w.z + a.w * w.w;
    }
    // reduce over the 16-lane group
#pragma unroll
    for (int off = 8; off > 0; off >>= 1) acc += __shfl_down(acc, off, 16);

    __shared__ float h[B];
    if (j == 0) h[b] = acc;
    __syncthreads();

    // BN stats over batch (16 values) — every thread redundantly (cheap)
    float mu = 0.0f;
#pragma unroll
    for (int i = 0; i < B; ++i) mu += h[i];
    mu *= (1.0f / (float)B);
    float var = 0.0f;
#pragma unroll
    for (int i = 0; i < B; ++i) { float d = h[i] - mu; var = fmaf(d, d, var); }
    var *= (1.0f / (float)B);
    const float inv = rsqrtf(var + 1e-5f);

    if (t < B) {
        float v = (h[t] - mu) * inv * g1[r] + b1[r];
        v = 0.5f * v * (1.0f + erff(v * 0.70710678118654752440f));  // exact-erf GELU
        h1[t * CR + r] = v;
    }
}

// ---------------------------------------------------------------------------
// Kernel 2b: gate[b][c] = sigmoid(BN2(dot(h1[b,:], w2[c,:]))). One block per c.
// 128 threads = 16 batches x 8 lanes; each lane covers 16 of 128 elements.
// ---------------------------------------------------------------------------
__global__ __launch_bounds__(128) void mlp2_kernel(
    const float* __restrict__ h1, const float* __restrict__ w2,
    const float* __restrict__ g2, const float* __restrict__ b2,
    float* __restrict__ gate) {
    const int c = blockIdx.x;      // 0..255
    const int t = threadIdx.x;     // 0..127
    const int b = t >> 3;          // 0..15
    const int j = t & 7;           // 0..7

    const float4* hv = (const float4*)(h1 + b * CR) + j * 4;
    const float4* wv = (const float4*)(w2 + c * CR) + j * 4;
    float acc = 0.0f;
#pragma unroll
    for (int k = 0; k < 4; ++k) {
        float4 a = hv[k], w = wv[k];
        acc += a.x * w.x + a.y * w.y + a.z * w.z + a.w * w.w;
    }
#pragma unroll
    for (int off = 4; off > 0; off >>= 1) acc += __shfl_down(acc, off, 8);

    __shared__ float h[B];
    if (j == 0) h[b] = acc;
    __syncthreads();

    float mu = 0.0f;
#pragma unroll
    for (int i = 0; i < B; ++i) mu += h[i];
    mu *= (1.0f / (float)B);
    float var = 0.0f;
#pragma unroll
    for (int i = 0; i < B; ++i) { float d = h[i] - mu; var = fmaf(d, d, var); }
    var *= (1.0f / (float)B);
    const float inv = rsqrtf(var + 1e-5f);

    if (t < B) {
        float v = (h[t] - mu) * inv * g2[c] + b2[c];
        gate[t * C + c] = 1.0f / (1.0f + expf(-v));
    }
}

// ---------------------------------------------------------------------------
// Kernel 3: out[b,c,:] = x[b,c,:] * gate[b,c]. One block per row, float4.
// ---------------------------------------------------------------------------
__global__ __launch_bounds__(THREADS) void scale_kernel(
    const float* __restrict__ x, const float* __restrict__ gate,
    float* __restrict__ out) {
    const int row = blockIdx.x;
    const int t = threadIdx.x;
    const float g = gate[row];
    const float4* xr = (const float4*)(x + (size_t)row * L);
    float4* orow = (float4*)(out + (size_t)row * L);
#pragma unroll
    for (int i = 0; i < ITERS; ++i) {
        float4 v = xr[t + i * THREADS];
        v.x *= g; v.y *= g; v.z *= g; v.w *= g;
        orow[t + i * THREADS] = v;
    }
}

extern "C" void kernel_launch(void* const* d_in, const int* in_sizes, int n_in,
                              void* d_out, int out_size, void* d_ws, size_t ws_size,
                              hipStream_t stream) {
    const float* x  = (const float*)d_in[0];
    const float* w1 = (const float*)d_in[1];
    const float* g1 = (const float*)d_in[2];
    const float* b1 = (const float*)d_in[3];
    const float* w2 = (const float*)d_in[4];
    const float* g2 = (const float*)d_in[5];
    const float* b2 = (const float*)d_in[6];
    float* out = (float*)d_out;

    float* s    = (float*)d_ws;          // NROW floats       [B,C]
    float* h1   = s + NROW;              // B*CR floats       [B,CR]
    float* gate = h1 + B * CR;           // NROW floats       [B,C]

    row_mean_kernel<<<NROW, THREADS, 0, stream>>>(x, s);
    mlp1_kernel<<<CR, 256, 0, stream>>>(s, w1, g1, b1, h1);
    mlp2_kernel<<<C, 128, 0, stream>>>(h1, w2, g2, b2, gate);
    scale_kernel<<<NROW, THREADS, 0, stream>>>(x, gate, out);
}